// Round 1
// baseline (1577.859 us; speedup 1.0000x reference)
//
#include <hip/hip_runtime.h>

// Problem dims
#define B_  4096
#define T_  128
#define NL  256
#define NS  64
#define NO  32
#define V_  64

typedef __bf16 bf16;
typedef bf16  bf16x8 __attribute__((ext_vector_type(8)));
typedef bf16  bf16x4 __attribute__((ext_vector_type(4)));
typedef float f32x4  __attribute__((ext_vector_type(4)));

// ---------------------------------------------------------------------------
// Split fp32 -> bf16 hi + bf16 lo (lo = exact residual rounded to bf16).
// hi+lo carries ~16 mantissa bits => 3-product MFMA reproduces fp32 GEMM to
// ~2^-16 relative, far inside the 6.4e-3 harness threshold even over 128
// recurrent steps.
// ---------------------------------------------------------------------------
__global__ void split_kernel(const float* __restrict__ src,
                             bf16* __restrict__ hi, bf16* __restrict__ lo,
                             int n4) {
    int t = blockIdx.x * blockDim.x + threadIdx.x;
    if (t >= n4) return;
    const float4 v = ((const float4*)src)[t];
    float vv[4] = {v.x, v.y, v.z, v.w};
    bf16x4 h, l;
#pragma unroll
    for (int i = 0; i < 4; i++) {
        bf16 hh = (bf16)vv[i];
        h[i] = hh;
        l[i] = (bf16)(vv[i] - (float)hh);
    }
    ((bf16x4*)hi)[t] = h;
    ((bf16x4*)lo)[t] = l;
}

// keep[s][j] = 1 iff no j2>j has out_idx[s][j2]==out_idx[s][j]
// (numpy fancy-assign y[:, idx] = probs : LAST duplicate wins)
__global__ void keep_kernel(const int* __restrict__ out_idx, int* __restrict__ keep) {
    int t = blockIdx.x * blockDim.x + threadIdx.x;
    if (t >= NS * NO) return;
    int s = t >> 5, j = t & 31;
    int v = out_idx[t];
    int k = 1;
    for (int j2 = j + 1; j2 < NO; j2++)
        if (out_idx[(s << 5) | j2] == v) k = 0;
    keep[t] = k;
}

__device__ __forceinline__ float fast_tanh(float z) {
    // 1 - 2/(e^{2z}+1); exact limits at +/-inf without fast-math
    float e = __expf(2.0f * z);
    return 1.0f - 2.0f / (e + 1.0f);
}

// ---------------------------------------------------------------------------
// Persistent per-block recurrence. Each block owns 16 batch rows; x lives in
// LDS (bf16 hi/lo, padded rows) across all 128 timesteps. No grid sync needed.
// 512 threads = 8 waves; wave w computes output cols [32w, 32w+32) of GEMM1.
// MFMA 16x16x32 bf16; layouts per guide §3 (A: m=lane&15,k=q*8+j;
// B: n=lane&15,k=q*8+j; D: col=lane&15,row=q*4+reg).
// ---------------------------------------------------------------------------
__launch_bounds__(512, 2)
__global__ void lalr_main(const float* __restrict__ latent0,
                          const float* __restrict__ b1,
                          const float* __restrict__ b2,
                          const int*   __restrict__ state_seq,
                          const int*   __restrict__ out_idx,
                          const bf16*  __restrict__ W1h, const bf16* __restrict__ W1l,
                          const bf16*  __restrict__ W2h, const bf16* __restrict__ W2l,
                          const int*   __restrict__ keep,
                          float* __restrict__ out) {
    __shared__ bf16  xh[16][264];   // row stride 528 B: 16B-aligned, bank-spread
    __shared__ bf16  xl[16][264];
    __shared__ float S[16][33];     // GEMM2 logits
    __shared__ float Yv[16][64];    // scattered output tile

    const int tid  = threadIdx.x;
    const int wave = tid >> 6;      // 0..7
    const int lane = tid & 63;
    const int l15  = lane & 15;
    const int q    = lane >> 4;     // quad 0..3
    const int r0   = blockIdx.x * 16;

    // ---- load latent0 rows, split into LDS ----
#pragma unroll
    for (int c = 0; c < 2; c++) {
        int flat = c * 2048 + tid * 4;           // element in [16][256]
        int r = flat >> 8, k = flat & 255;
        float4 v = *(const float4*)(latent0 + (size_t)(r0 + r) * NL + k);
        float vv[4] = {v.x, v.y, v.z, v.w};
        bf16x4 h, l;
#pragma unroll
        for (int i = 0; i < 4; i++) {
            bf16 hh = (bf16)vv[i];
            h[i] = hh;
            l[i] = (bf16)(vv[i] - (float)hh);
        }
        *(bf16x4*)(&xh[r][k]) = h;
        *(bf16x4*)(&xl[r][k]) = l;
    }
    __syncthreads();

    for (int t = 0; t < T_; t++) {
        const int s = state_seq[t];

        // ---- GEMM1: x_new_pre = X @ W1[s]^T  (M=16, N=256, K=256) ----
        f32x4 acc[2];
        acc[0] = (f32x4){0.f, 0.f, 0.f, 0.f};
        acc[1] = (f32x4){0.f, 0.f, 0.f, 0.f};
        const bf16* w1hs = W1h + ((size_t)s << 16);
        const bf16* w1ls = W1l + ((size_t)s << 16);
#pragma unroll
        for (int ks = 0; ks < 8; ks++) {
            const int kk = ks * 32 + q * 8;
            bf16x8 ah = *(const bf16x8*)(&xh[l15][kk]);
            bf16x8 al = *(const bf16x8*)(&xl[l15][kk]);
#pragma unroll
            for (int n = 0; n < 2; n++) {
                const int col = wave * 32 + n * 16 + l15;   // W1 row = output col
                bf16x8 bh = *(const bf16x8*)(w1hs + col * NL + kk);
                bf16x8 bl = *(const bf16x8*)(w1ls + col * NL + kk);
                acc[n] = __builtin_amdgcn_mfma_f32_16x16x32_bf16(ah, bh, acc[n], 0, 0, 0);
                acc[n] = __builtin_amdgcn_mfma_f32_16x16x32_bf16(al, bh, acc[n], 0, 0, 0);
                acc[n] = __builtin_amdgcn_mfma_f32_16x16x32_bf16(ah, bl, acc[n], 0, 0, 0);
            }
        }
        __syncthreads();   // all reads of x done; also orders prev Yv copy

        // ---- bias + tanh + re-split x_new into LDS; zero Yv ----
        if (tid < 256) ((f32x4*)&Yv[0][0])[tid] = (f32x4){0.f, 0.f, 0.f, 0.f};
#pragma unroll
        for (int n = 0; n < 2; n++) {
            const int col  = wave * 32 + n * 16 + l15;
            const float bias = b1[s * NL + col];
#pragma unroll
            for (int reg = 0; reg < 4; reg++) {
                const int r = q * 4 + reg;               // D row = batch row
                float h = fast_tanh(acc[n][reg] + bias);
                bf16 hh = (bf16)h;
                xh[r][col] = hh;
                xl[r][col] = (bf16)(h - (float)hh);
            }
        }
        __syncthreads();

        // ---- GEMM2: logits = X_new @ W2[s]^T  (M=16, N=32, K=256), waves 0,1 ----
        if (wave < 2) {
            f32x4 acc2 = (f32x4){0.f, 0.f, 0.f, 0.f};
            const bf16* w2hs = W2h + (size_t)s * (NO * NL);
            const bf16* w2ls = W2l + (size_t)s * (NO * NL);
            const int o = wave * 16 + l15;
#pragma unroll
            for (int ks = 0; ks < 8; ks++) {
                const int kk = ks * 32 + q * 8;
                bf16x8 ah = *(const bf16x8*)(&xh[l15][kk]);
                bf16x8 al = *(const bf16x8*)(&xl[l15][kk]);
                bf16x8 bh = *(const bf16x8*)(w2hs + o * NL + kk);
                bf16x8 bl = *(const bf16x8*)(w2ls + o * NL + kk);
                acc2 = __builtin_amdgcn_mfma_f32_16x16x32_bf16(ah, bh, acc2, 0, 0, 0);
                acc2 = __builtin_amdgcn_mfma_f32_16x16x32_bf16(al, bh, acc2, 0, 0, 0);
                acc2 = __builtin_amdgcn_mfma_f32_16x16x32_bf16(ah, bl, acc2, 0, 0, 0);
            }
            const float bias2 = b2[s * NO + o];
#pragma unroll
            for (int reg = 0; reg < 4; reg++)
                S[q * 4 + reg][o] = acc2[reg] + bias2;
        }
        __syncthreads();

        // ---- softmax over 32 + masked scatter (last-dup-wins) ----
        if (tid < 256) {
            const int r  = tid >> 4;       // 0..15
            const int j0 = tid & 15;
            float v0 = S[r][j0], v1 = S[r][j0 + 16];
            float m = fmaxf(v0, v1);
#pragma unroll
            for (int d = 1; d < 16; d <<= 1) m = fmaxf(m, __shfl_xor(m, d));
            float e0 = __expf(v0 - m), e1 = __expf(v1 - m);
            float sum = e0 + e1;
#pragma unroll
            for (int d = 1; d < 16; d <<= 1) sum += __shfl_xor(sum, d);
            float inv = 1.0f / sum;
            const int base = s * NO;
            if (keep[base + j0])      Yv[r][out_idx[base + j0]]      = e0 * inv;
            if (keep[base + j0 + 16]) Yv[r][out_idx[base + j0 + 16]] = e1 * inv;
        }
        __syncthreads();

        // ---- coalesced store of y[r0..r0+15][t][0..63] ----
        if (tid < 256) {
            const int r = tid >> 4;
            const int c = (tid & 15) * 4;
            f32x4 v = *(const f32x4*)(&Yv[r][c]);
            *(f32x4*)(out + ((size_t)(r0 + r) * T_ + t) * V_ + c) = v;
        }
    }
}

extern "C" void kernel_launch(void* const* d_in, const int* in_sizes, int n_in,
                              void* d_out, int out_size, void* d_ws, size_t ws_size,
                              hipStream_t stream) {
    const float* latent0   = (const float*)d_in[0];
    const float* W1        = (const float*)d_in[1];
    const float* b1        = (const float*)d_in[2];
    const float* W2        = (const float*)d_in[3];
    const float* b2        = (const float*)d_in[4];
    const int*   state_seq = (const int*)d_in[5];
    const int*   out_idx   = (const int*)d_in[6];
    float* out = (float*)d_out;

    // workspace layout (recomputed every call; ws is re-poisoned)
    bf16* W1h  = (bf16*)d_ws;
    bf16* W1l  = W1h + (size_t)NS * NL * NL;
    bf16* W2h  = W1l + (size_t)NS * NL * NL;
    bf16* W2l  = W2h + (size_t)NS * NO * NL;
    int*  keep = (int*)(W2l + (size_t)NS * NO * NL);

    const int n4_w1 = NS * NL * NL / 4;   // 1,048,576
    const int n4_w2 = NS * NO * NL / 4;   // 131,072
    split_kernel<<<n4_w1 / 256, 256, 0, stream>>>(W1, W1h, W1l, n4_w1);
    split_kernel<<<n4_w2 / 256, 256, 0, stream>>>(W2, W2h, W2l, n4_w2);
    keep_kernel<<<(NS * NO + 255) / 256, 256, 0, stream>>>(out_idx, keep);

    lalr_main<<<B_ / 16, 512, 0, stream>>>(latent0, b1, b2, state_seq, out_idx,
                                           W1h, W1l, W2h, W2l, keep, out);
}

// Round 2
// 1504.815 us; speedup vs baseline: 1.0485x; 1.0485x over previous
//
#include <hip/hip_runtime.h>

// Problem dims
#define B_  4096
#define T_  128
#define NL  256
#define NS  64
#define NO  32
#define V_  64
#define RB  32            // rows per block
#define NBLK (B_ / RB)    // 128 blocks

typedef __bf16 bf16;
typedef bf16  bf16x8 __attribute__((ext_vector_type(8)));
typedef bf16  bf16x4 __attribute__((ext_vector_type(4)));
typedef float f32x4  __attribute__((ext_vector_type(4)));

// ---------------------------------------------------------------------------
// Split fp32 -> bf16 hi + bf16 lo (lo = exact residual rounded to bf16).
// 3-product MFMA reproduces fp32 GEMM to ~2^-16 relative.
// ---------------------------------------------------------------------------
__global__ void split_kernel(const float* __restrict__ src,
                             bf16* __restrict__ hi, bf16* __restrict__ lo,
                             int n4) {
    int t = blockIdx.x * blockDim.x + threadIdx.x;
    if (t >= n4) return;
    const float4 v = ((const float4*)src)[t];
    float vv[4] = {v.x, v.y, v.z, v.w};
    bf16x4 h, l;
#pragma unroll
    for (int i = 0; i < 4; i++) {
        bf16 hh = (bf16)vv[i];
        h[i] = hh;
        l[i] = (bf16)(vv[i] - (float)hh);
    }
    ((bf16x4*)hi)[t] = h;
    ((bf16x4*)lo)[t] = l;
}

// inv[s][v] = last j with out_idx[s][j]==v, else -1 (numpy last-dup-wins)
__global__ void inv_kernel(const int* __restrict__ out_idx, int* __restrict__ inv) {
    int t = blockIdx.x * blockDim.x + threadIdx.x;
    if (t >= NS * V_) return;
    int s = t >> 6, v = t & 63;
    int jf = -1;
#pragma unroll
    for (int j = 0; j < NO; j++)
        if (out_idx[(s << 5) | j] == v) jf = j;
    inv[t] = jf;
}

__device__ __forceinline__ float fast_tanh(float z) {
    float e = __expf(2.0f * z);
    return 1.0f - 2.0f / (e + 1.0f);
}

// ---------------------------------------------------------------------------
// Persistent per-block recurrence, R=32 rows/block, 128 blocks.
// Pipeline per iteration i (2 barriers):
//   phase1: GEMM2(i-1) K-split over all 8 waves -> Spart ; GEMM1(i) -> regs
//   barrier
//   phase2: tanh+split -> x[nxt] ; softmax(Spart)+b2 -> P
//   barrier
//   phase3: store y(i-1) via inv table
// x double-buffered in LDS so phase2 writes never collide with phase1 reads.
// ---------------------------------------------------------------------------
__launch_bounds__(512, 2)
__global__ void lalr_main(const float* __restrict__ latent0,
                          const float* __restrict__ b1,
                          const float* __restrict__ b2,
                          const int*   __restrict__ state_seq,
                          const bf16*  __restrict__ W1h, const bf16* __restrict__ W1l,
                          const bf16*  __restrict__ W2h, const bf16* __restrict__ W2l,
                          const int*   __restrict__ inv,
                          float* __restrict__ out) {
    __shared__ bf16  xh[2][RB][264];     // 33.0 KB  (row stride 528 B)
    __shared__ bf16  xl[2][RB][264];     // 33.0 KB
    __shared__ float Spart[8][RB][33];   // 33.8 KB  GEMM2 K-partials
    __shared__ float P[RB][33];          // 4.2 KB   softmaxed probs

    const int tid  = threadIdx.x;
    const int wave = tid >> 6;           // 0..7
    const int lane = tid & 63;
    const int l15  = lane & 15;
    const int q    = lane >> 4;          // 0..3
    const int r0   = blockIdx.x * RB;

    // ---- load latent0 rows, split into x[0] ----
#pragma unroll
    for (int c = 0; c < 4; c++) {
        int flat = c * 2048 + tid * 4;           // element in [32][256]
        int r = flat >> 8, k = flat & 255;
        float4 v = *(const float4*)(latent0 + (size_t)(r0 + r) * NL + k);
        float vv[4] = {v.x, v.y, v.z, v.w};
        bf16x4 h, l;
#pragma unroll
        for (int ii = 0; ii < 4; ii++) {
            bf16 hh = (bf16)vv[ii];
            h[ii] = hh;
            l[ii] = (bf16)(vv[ii] - (float)hh);
        }
        *(bf16x4*)(&xh[0][r][k]) = h;
        *(bf16x4*)(&xl[0][r][k]) = l;
    }
    __syncthreads();

    int cur = 0;
    int s_cur = state_seq[0];
    int s_prev = 0;

    for (int i = 0; i <= T_; i++) {
        const int s_nxt = (i + 1 < T_) ? state_seq[i + 1] : 0;

        // =============== phase 1 ===============
        // GEMM2 for step i-1: K-slice [32*wave, 32*wave+32), tiles 2x2 of 16x16x32
        f32x4 a2[2][2];
        if (i > 0) {
            const bf16* w2hs = W2h + (size_t)s_prev * (NO * NL);
            const bf16* w2ls = W2l + (size_t)s_prev * (NO * NL);
            const int kk = wave * 32 + q * 8;
            bf16x8 ah[2], al[2], bh[2], bl[2];
#pragma unroll
            for (int mt = 0; mt < 2; mt++) {
                ah[mt] = *(const bf16x8*)(&xh[cur][16 * mt + l15][kk]);
                al[mt] = *(const bf16x8*)(&xl[cur][16 * mt + l15][kk]);
            }
#pragma unroll
            for (int nt = 0; nt < 2; nt++) {
                const int o = 16 * nt + l15;
                bh[nt] = *(const bf16x8*)(w2hs + o * NL + kk);
                bl[nt] = *(const bf16x8*)(w2ls + o * NL + kk);
            }
#pragma unroll
            for (int mt = 0; mt < 2; mt++)
#pragma unroll
                for (int nt = 0; nt < 2; nt++) {
                    a2[mt][nt] = (f32x4){0.f, 0.f, 0.f, 0.f};
                    a2[mt][nt] = __builtin_amdgcn_mfma_f32_16x16x32_bf16(ah[mt], bh[nt], a2[mt][nt], 0, 0, 0);
                    a2[mt][nt] = __builtin_amdgcn_mfma_f32_16x16x32_bf16(al[mt], bh[nt], a2[mt][nt], 0, 0, 0);
                    a2[mt][nt] = __builtin_amdgcn_mfma_f32_16x16x32_bf16(ah[mt], bl[nt], a2[mt][nt], 0, 0, 0);
                }
        }

        // GEMM1 for step i: cols [32*wave, 32*wave+32), full K=256
        f32x4 a1[2][2];
        if (i < T_) {
            const bf16* w1hs = W1h + ((size_t)s_cur << 16);
            const bf16* w1ls = W1l + ((size_t)s_cur << 16);
#pragma unroll
            for (int mt = 0; mt < 2; mt++)
#pragma unroll
                for (int nt = 0; nt < 2; nt++)
                    a1[mt][nt] = (f32x4){0.f, 0.f, 0.f, 0.f};
#pragma unroll
            for (int ks = 0; ks < 8; ks++) {
                const int kk = ks * 32 + q * 8;
                bf16x8 ah[2], al[2], bh[2], bl[2];
#pragma unroll
                for (int mt = 0; mt < 2; mt++) {
                    ah[mt] = *(const bf16x8*)(&xh[cur][16 * mt + l15][kk]);
                    al[mt] = *(const bf16x8*)(&xl[cur][16 * mt + l15][kk]);
                }
#pragma unroll
                for (int nt = 0; nt < 2; nt++) {
                    const int col = 32 * wave + 16 * nt + l15;
                    bh[nt] = *(const bf16x8*)(w1hs + col * NL + kk);
                    bl[nt] = *(const bf16x8*)(w1ls + col * NL + kk);
                }
#pragma unroll
                for (int mt = 0; mt < 2; mt++)
#pragma unroll
                    for (int nt = 0; nt < 2; nt++) {
                        a1[mt][nt] = __builtin_amdgcn_mfma_f32_16x16x32_bf16(ah[mt], bh[nt], a1[mt][nt], 0, 0, 0);
                        a1[mt][nt] = __builtin_amdgcn_mfma_f32_16x16x32_bf16(al[mt], bh[nt], a1[mt][nt], 0, 0, 0);
                        a1[mt][nt] = __builtin_amdgcn_mfma_f32_16x16x32_bf16(ah[mt], bl[nt], a1[mt][nt], 0, 0, 0);
                    }
            }
        }

        // write GEMM2 partials (D: col=lane&15, row=q*4+reg)
        if (i > 0) {
#pragma unroll
            for (int mt = 0; mt < 2; mt++)
#pragma unroll
                for (int nt = 0; nt < 2; nt++)
#pragma unroll
                    for (int reg = 0; reg < 4; reg++)
                        Spart[wave][16 * mt + q * 4 + reg][16 * nt + l15] = a2[mt][nt][reg];
        }
        __syncthreads();   // barrier 1

        // =============== phase 2 ===============
        if (i < T_) {
#pragma unroll
            for (int nt = 0; nt < 2; nt++) {
                const int col  = 32 * wave + 16 * nt + l15;
                const float bias = b1[s_cur * NL + col];
#pragma unroll
                for (int mt = 0; mt < 2; mt++)
#pragma unroll
                    for (int reg = 0; reg < 4; reg++) {
                        const int row = 16 * mt + q * 4 + reg;
                        float h = fast_tanh(a1[mt][nt][reg] + bias);
                        bf16 hh = (bf16)h;
                        xh[cur ^ 1][row][col] = hh;
                        xl[cur ^ 1][row][col] = (bf16)(h - (float)hh);
                    }
            }
        }
        if (i > 0) {
            // softmax: thread -> (r = tid>>4 in 0..31, j0 = tid&15), j = {j0, j0+16}
            const int r  = tid >> 4;
            const int j0 = tid & 15;
            float v0 = b2[s_prev * NO + j0];
            float v1 = b2[s_prev * NO + j0 + 16];
#pragma unroll
            for (int w = 0; w < 8; w++) {
                v0 += Spart[w][r][j0];
                v1 += Spart[w][r][j0 + 16];
            }
            float m = fmaxf(v0, v1);
#pragma unroll
            for (int d = 1; d < 16; d <<= 1) m = fmaxf(m, __shfl_xor(m, d));
            float e0 = __expf(v0 - m), e1 = __expf(v1 - m);
            float sum = e0 + e1;
#pragma unroll
            for (int d = 1; d < 16; d <<= 1) sum += __shfl_xor(sum, d);
            float invs = 1.0f / sum;
            P[r][j0]      = e0 * invs;
            P[r][j0 + 16] = e1 * invs;
        }
        __syncthreads();   // barrier 2

        // =============== phase 3 ===============
        if (i > 0) {
            const int r  = tid >> 4;
            const int c4 = (tid & 15) * 4;
            const int4 iv = *(const int4*)(inv + s_prev * V_ + c4);
            float4 o;
            o.x = (iv.x >= 0) ? P[r][iv.x] : 0.f;
            o.y = (iv.y >= 0) ? P[r][iv.y] : 0.f;
            o.z = (iv.z >= 0) ? P[r][iv.z] : 0.f;
            o.w = (iv.w >= 0) ? P[r][iv.w] : 0.f;
            *(float4*)(out + ((size_t)(r0 + r) * T_ + (i - 1)) * V_ + c4) = o;
        }

        cur ^= 1;
        s_prev = s_cur;
        s_cur  = s_nxt;
    }
}

extern "C" void kernel_launch(void* const* d_in, const int* in_sizes, int n_in,
                              void* d_out, int out_size, void* d_ws, size_t ws_size,
                              hipStream_t stream) {
    const float* latent0   = (const float*)d_in[0];
    const float* W1        = (const float*)d_in[1];
    const float* b1        = (const float*)d_in[2];
    const float* W2        = (const float*)d_in[3];
    const float* b2        = (const float*)d_in[4];
    const int*   state_seq = (const int*)d_in[5];
    const int*   out_idx   = (const int*)d_in[6];
    float* out = (float*)d_out;

    bf16* W1h  = (bf16*)d_ws;
    bf16* W1l  = W1h + (size_t)NS * NL * NL;
    bf16* W2h  = W1l + (size_t)NS * NL * NL;
    bf16* W2l  = W2h + (size_t)NS * NO * NL;
    int*  inv  = (int*)(W2l + (size_t)NS * NO * NL);

    const int n4_w1 = NS * NL * NL / 4;
    const int n4_w2 = NS * NO * NL / 4;
    split_kernel<<<n4_w1 / 256, 256, 0, stream>>>(W1, W1h, W1l, n4_w1);
    split_kernel<<<n4_w2 / 256, 256, 0, stream>>>(W2, W2h, W2l, n4_w2);
    inv_kernel<<<(NS * V_ + 255) / 256, 256, 0, stream>>>(out_idx, inv);

    lalr_main<<<NBLK, 512, 0, stream>>>(latent0, b1, b2, state_seq,
                                        W1h, W1l, W2h, W2l, inv, out);
}

// Round 3
// 706.756 us; speedup vs baseline: 2.2325x; 2.1292x over previous
//
#include <hip/hip_runtime.h>

// Problem dims
#define B_  4096
#define T_  128
#define NL  256
#define NS  64
#define NO  32
#define V_  64
#define RB  16            // rows per block
#define NBLK (B_ / RB)    // 256 blocks

typedef __bf16 bf16;
typedef bf16  bf16x8 __attribute__((ext_vector_type(8)));
typedef bf16  bf16x4 __attribute__((ext_vector_type(4)));
typedef float f32x4  __attribute__((ext_vector_type(4)));

#define MF(a, b, c) __builtin_amdgcn_mfma_f32_16x16x32_bf16(a, b, c, 0, 0, 0)

// ---------------------------------------------------------------------------
// Split fp32 weights -> bf16 hi/lo planes in MFMA A-fragment order:
//   dest[(((s*NT + t)*8 + ks)*512) + L*8 + j] = W[s][t*16 + (L&15)][ks*32 + (L>>4)*8 + j]
// so a wave's fragment load is one contiguous 1 KB global_load_dwordx4.
// ---------------------------------------------------------------------------
template <int TSHIFT>
__global__ void split_w_frag(const float* __restrict__ src,
                             bf16* __restrict__ hi, bf16* __restrict__ lo,
                             int total4) {
    int t4 = blockIdx.x * blockDim.x + threadIdx.x;
    if (t4 >= total4) return;
    const int jb   = (t4 & 1) * 4;
    const int L    = (t4 >> 1) & 63;
    const int ks   = (t4 >> 7) & 7;
    const int rest = t4 >> 10;
    const int t    = rest & ((1 << TSHIFT) - 1);
    const int s    = rest >> TSHIFT;
    const int row  = ((s << TSHIFT) + t) * 16 + (L & 15);
    const int k    = ks * 32 + (L >> 4) * 8 + jb;
    const float4 v = *(const float4*)(src + (size_t)row * NL + k);
    float vv[4] = {v.x, v.y, v.z, v.w};
    bf16x4 h, l;
#pragma unroll
    for (int e = 0; e < 4; e++) {
        bf16 hh = (bf16)vv[e];
        h[e] = hh;
        l[e] = (bf16)(vv[e] - (float)hh);
    }
    *(bf16x4*)(hi + (size_t)t4 * 4) = h;
    *(bf16x4*)(lo + (size_t)t4 * 4) = l;
}

// inv[s][v] = last j with out_idx[s][j]==v, else -1 (numpy last-dup-wins)
__global__ void inv_kernel(const int* __restrict__ out_idx, int* __restrict__ inv) {
    int t = blockIdx.x * blockDim.x + threadIdx.x;
    if (t >= NS * V_) return;
    int s = t >> 6, v = t & 63;
    int jf = -1;
#pragma unroll
    for (int j = 0; j < NO; j++)
        if (out_idx[(s << 5) | j] == v) jf = j;
    inv[t] = jf;
}

__device__ __forceinline__ float fast_tanh(float z) {
    float e = __expf(2.0f * z);
    return 1.0f - 2.0f / (e + 1.0f);
}

// x fragment-order address for element (batch row n, k = t*16 + q*4 + reg..):
// addr = (t>>1)*512 + ((t&1)*2 + (q>>1))*128 + n*8 + (q&1)*4   (+reg contiguous)
__device__ __forceinline__ int xaddr(int t, int q, int n) {
    return ((t >> 1) * 512) + (((t & 1) * 2 + (q >> 1)) * 128) + n * 8 + (q & 1) * 4;
}

// ---------------------------------------------------------------------------
// Persistent per-block recurrence, RB=16 rows/block, 256 blocks, 8 waves.
// One barrier per step. MFMA operands swapped (A=W frag, B=x frag) so
// D[row=out_col][col=batch_row]: tanh writeback = 4x ds_write_b64, and x is
// kept in fragment order => ds_read_b128 at lane*16, conflict-free.
// Software-pipelined weight loads (2-slot ring + cross-barrier prefetch).
// ---------------------------------------------------------------------------
__launch_bounds__(512, 2)
__global__ void lalr_main(const float* __restrict__ latent0,
                          const float* __restrict__ b1,
                          const float* __restrict__ b2,
                          const int*   __restrict__ state_seq,
                          const int*   __restrict__ inv,
                          const bf16*  __restrict__ W1h, const bf16* __restrict__ W1l,
                          const bf16*  __restrict__ W2h, const bf16* __restrict__ W2l,
                          float* __restrict__ out) {
    __shared__ bf16  xh[2][4096];        // 16 KB  (frag order, double buffered)
    __shared__ bf16  xl[2][4096];        // 16 KB
    __shared__ float Sp[2][8][16][36];   // 36.9 KB GEMM2 K-partials (pad 36)

    const int tid  = threadIdx.x;
    const int wave = tid >> 6;
    const int lane = tid & 63;
    const int n    = lane & 15;          // batch row (B-frag n / A-frag m)
    const int q    = lane >> 4;          // quad
    const int r0   = blockIdx.x * RB;

    // ---- init: latent0 -> x[0] fragments ----
#pragma unroll
    for (int tt = 0; tt < 2; tt++) {
        const int t = wave * 2 + tt;
        float4 v = *(const float4*)(latent0 + (size_t)(r0 + n) * NL + t * 16 + q * 4);
        float vv[4] = {v.x, v.y, v.z, v.w};
        bf16x4 hv, lv;
#pragma unroll
        for (int e = 0; e < 4; e++) {
            bf16 hh = (bf16)vv[e];
            hv[e] = hh;
            lv[e] = (bf16)(vv[e] - (float)hh);
        }
        const int a = xaddr(t, q, n);
        *(bf16x4*)(&xh[0][a]) = hv;
        *(bf16x4*)(&xl[0][a]) = lv;
    }

    int s0 = state_seq[0], s1 = -1, s2 = -1;

    // GEMM1 pipeline: preload ks=0,1 for s0
    bf16x8 pwh[2][2], pwl[2][2];
    const bf16* w1hb = W1h + ((size_t)(s0 * 16 + wave * 2) * 8) * 512;
    const bf16* w1lb = W1l + ((size_t)(s0 * 16 + wave * 2) * 8) * 512;
#pragma unroll
    for (int p = 0; p < 2; p++) {
        pwh[p][0] = *(const bf16x8*)(w1hb + p * 512 + lane * 8);
        pwh[p][1] = *(const bf16x8*)(w1hb + (8 + p) * 512 + lane * 8);
        pwl[p][0] = *(const bf16x8*)(w1lb + p * 512 + lane * 8);
        pwl[p][1] = *(const bf16x8*)(w1lb + (8 + p) * 512 + lane * 8);
    }
    bf16x8 w2hr[2], w2lr[2];   // GEMM2 frags (loaded each iter-end for next iter)

    __syncthreads();

    for (int i = 0; i <= T_ + 1; i++) {
        const int ib  = i & 1;
        const int cur = ib;               // x buffer read this iteration

        // ---- GEMM1 (state s0): pre-activations for step i ----
        f32x4 acc1[2];
        if (s0 >= 0) {
            acc1[0] = (f32x4){0.f, 0.f, 0.f, 0.f};
            acc1[1] = (f32x4){0.f, 0.f, 0.f, 0.f};
#pragma unroll
            for (int ks = 0; ks < 8; ks++) {
                bf16x8 xa = *(const bf16x8*)(&xh[cur][ks * 512 + lane * 8]);
                bf16x8 xb = *(const bf16x8*)(&xl[cur][ks * 512 + lane * 8]);
                const int sl = ks & 1;
                bf16x8 wh0 = pwh[sl][0], wh1 = pwh[sl][1];
                bf16x8 wl0 = pwl[sl][0], wl1 = pwl[sl][1];
                if (ks < 6) {
                    pwh[sl][0] = *(const bf16x8*)(w1hb + (ks + 2) * 512 + lane * 8);
                    pwh[sl][1] = *(const bf16x8*)(w1hb + (8 + ks + 2) * 512 + lane * 8);
                    pwl[sl][0] = *(const bf16x8*)(w1lb + (ks + 2) * 512 + lane * 8);
                    pwl[sl][1] = *(const bf16x8*)(w1lb + (8 + ks + 2) * 512 + lane * 8);
                }
                acc1[0] = MF(wh0, xa, acc1[0]);
                acc1[0] = MF(wl0, xa, acc1[0]);
                acc1[0] = MF(wh0, xb, acc1[0]);
                acc1[1] = MF(wh1, xa, acc1[1]);
                acc1[1] = MF(wl1, xa, acc1[1]);
                acc1[1] = MF(wh1, xb, acc1[1]);
            }
        }

        // ---- GEMM2 (state s1, K-split: this wave handles ks=wave) ----
        if (s1 >= 0) {
            bf16x8 xa = *(const bf16x8*)(&xh[cur][wave * 512 + lane * 8]);
            bf16x8 xb = *(const bf16x8*)(&xl[cur][wave * 512 + lane * 8]);
#pragma unroll
            for (int t = 0; t < 2; t++) {
                f32x4 a2 = (f32x4){0.f, 0.f, 0.f, 0.f};
                a2 = MF(w2hr[t], xa, a2);
                a2 = MF(w2lr[t], xa, a2);
                a2 = MF(w2hr[t], xb, a2);
                if (wave == 0) {
                    float4 bb = *(const float4*)(b2 + s1 * NO + t * 16 + q * 4);
                    a2[0] += bb.x; a2[1] += bb.y; a2[2] += bb.z; a2[3] += bb.w;
                }
                *(f32x4*)(&Sp[ib][wave][n][t * 16 + q * 4]) = a2;
            }
        }

        // ---- softmax + shfl-scatter + store for step i-2 (waves 0-3) ----
        if (s2 >= 0 && tid < 256) {
            const int r  = tid >> 4;
            const int j0 = tid & 15;
            const int pb = (i - 1) & 1;
            float v0 = 0.f, v1 = 0.f;
#pragma unroll
            for (int w = 0; w < 8; w++) {
                v0 += Sp[pb][w][r][j0];
                v1 += Sp[pb][w][r][j0 + 16];
            }
            float m = fmaxf(v0, v1);
#pragma unroll
            for (int d = 1; d < 16; d <<= 1) m = fmaxf(m, __shfl_xor(m, d));
            float e0 = __expf(v0 - m), e1 = __expf(v1 - m);
            float su = e0 + e1;
#pragma unroll
            for (int d = 1; d < 16; d <<= 1) su += __shfl_xor(su, d);
            float is = 1.0f / su;
            float p0 = e0 * is, p1 = e1 * is;
            const int gb = lane & 48;     // 16-lane group base
            int4 iv4 = *(const int4*)(inv + s2 * V_ + j0 * 4);
            int ivv[4] = {iv4.x, iv4.y, iv4.z, iv4.w};
            float o[4];
#pragma unroll
            for (int e = 0; e < 4; e++) {
                float ga = __shfl(p0, gb + (ivv[e] & 15));
                float gc = __shfl(p1, gb + (ivv[e] & 15));
                o[e] = (ivv[e] < 0) ? 0.f : ((ivv[e] < 16) ? ga : gc);
            }
            *(float4*)(out + ((size_t)(r0 + r) * T_ + (i - 2)) * V_ + j0 * 4) = *(float4*)o;
        }

        // ---- tanh + hi/lo split -> x[cur^1] ----
        if (s0 >= 0) {
#pragma unroll
            for (int tt = 0; tt < 2; tt++) {
                const int t = wave * 2 + tt;
                float4 bb = *(const float4*)(b1 + s0 * NL + t * 16 + q * 4);
                float bv[4] = {bb.x, bb.y, bb.z, bb.w};
                bf16x4 hv, lv;
#pragma unroll
                for (int e = 0; e < 4; e++) {
                    float h = fast_tanh(acc1[tt][e] + bv[e]);
                    bf16 hh = (bf16)h;
                    hv[e] = hh;
                    lv[e] = (bf16)(h - (float)hh);
                }
                const int a = xaddr(t, q, n);
                *(bf16x4*)(&xh[cur ^ 1][a]) = hv;
                *(bf16x4*)(&xl[cur ^ 1][a]) = lv;
            }
        }

        // ---- rotate states + cross-barrier prefetch for next iteration ----
        const int ns0 = (i + 1 < T_) ? state_seq[i + 1] : -1;
        if (s0 >= 0) {   // next iteration's GEMM2 state = current s0
            const bf16* w2hb = W2h + ((size_t)(s0 * 2) * 8 + wave) * 512;
            const bf16* w2lb = W2l + ((size_t)(s0 * 2) * 8 + wave) * 512;
            w2hr[0] = *(const bf16x8*)(w2hb + lane * 8);
            w2hr[1] = *(const bf16x8*)(w2hb + 8 * 512 + lane * 8);
            w2lr[0] = *(const bf16x8*)(w2lb + lane * 8);
            w2lr[1] = *(const bf16x8*)(w2lb + 8 * 512 + lane * 8);
        }
        if (ns0 >= 0) {
            w1hb = W1h + ((size_t)(ns0 * 16 + wave * 2) * 8) * 512;
            w1lb = W1l + ((size_t)(ns0 * 16 + wave * 2) * 8) * 512;
#pragma unroll
            for (int p = 0; p < 2; p++) {
                pwh[p][0] = *(const bf16x8*)(w1hb + p * 512 + lane * 8);
                pwh[p][1] = *(const bf16x8*)(w1hb + (8 + p) * 512 + lane * 8);
                pwl[p][0] = *(const bf16x8*)(w1lb + p * 512 + lane * 8);
                pwl[p][1] = *(const bf16x8*)(w1lb + (8 + p) * 512 + lane * 8);
            }
        }
        s2 = s1; s1 = s0; s0 = ns0;
        __syncthreads();
    }
}

extern "C" void kernel_launch(void* const* d_in, const int* in_sizes, int n_in,
                              void* d_out, int out_size, void* d_ws, size_t ws_size,
                              hipStream_t stream) {
    const float* latent0   = (const float*)d_in[0];
    const float* W1        = (const float*)d_in[1];
    const float* b1        = (const float*)d_in[2];
    const float* W2        = (const float*)d_in[3];
    const float* b2        = (const float*)d_in[4];
    const int*   state_seq = (const int*)d_in[5];
    const int*   out_idx   = (const int*)d_in[6];
    float* out = (float*)d_out;

    bf16* W1h = (bf16*)d_ws;
    bf16* W1l = W1h + (size_t)NS * NL * NL;
    bf16* W2h = W1l + (size_t)NS * NL * NL;
    bf16* W2l = W2h + (size_t)NS * NO * NL;
    int*  inv = (int*)(W2l + (size_t)NS * NO * NL);

    const int n4_w1 = NS * NL * NL / 4;   // 1,048,576
    const int n4_w2 = NS * NO * NL / 4;   // 131,072
    split_w_frag<4><<<n4_w1 / 256, 256, 0, stream>>>(W1, W1h, W1l, n4_w1);
    split_w_frag<1><<<n4_w2 / 256, 256, 0, stream>>>(W2, W2h, W2l, n4_w2);
    inv_kernel<<<(NS * V_ + 255) / 256, 256, 0, stream>>>(out_idx, inv);

    lalr_main<<<NBLK, 512, 0, stream>>>(latent0, b1, b2, state_seq, inv,
                                        W1h, W1l, W2h, W2l, out);
}

// Round 4
// 580.238 us; speedup vs baseline: 2.7193x; 1.2180x over previous
//
#include <hip/hip_runtime.h>

// Problem dims
#define B_  4096
#define T_  128
#define NL  256
#define NS  64
#define NO  32
#define V_  64
#define RB  16            // rows per block
#define NBLK (B_ / RB)    // 256 blocks

typedef __bf16 bf16;
typedef bf16  bf16x8 __attribute__((ext_vector_type(8)));
typedef bf16  bf16x4 __attribute__((ext_vector_type(4)));
typedef float f32x4  __attribute__((ext_vector_type(4)));

#define MF(a, b, c) __builtin_amdgcn_mfma_f32_16x16x32_bf16(a, b, c, 0, 0, 0)

// ---------------------------------------------------------------------------
// Split fp32 weights -> bf16 hi/lo planes in MFMA A-fragment order:
//   dest[(((s*NT + t)*8 + ks)*512) + L*8 + j] = W[s][t*16 + (L&15)][ks*32 + (L>>4)*8 + j]
// so a wave's fragment load is one contiguous 1 KB global_load_dwordx4.
// ---------------------------------------------------------------------------
template <int TSHIFT>
__global__ void split_w_frag(const float* __restrict__ src,
                             bf16* __restrict__ hi, bf16* __restrict__ lo,
                             int total4) {
    int t4 = blockIdx.x * blockDim.x + threadIdx.x;
    if (t4 >= total4) return;
    const int jb   = (t4 & 1) * 4;
    const int L    = (t4 >> 1) & 63;
    const int ks   = (t4 >> 7) & 7;
    const int rest = t4 >> 10;
    const int t    = rest & ((1 << TSHIFT) - 1);
    const int s    = rest >> TSHIFT;
    const int row  = ((s << TSHIFT) + t) * 16 + (L & 15);
    const int k    = ks * 32 + (L >> 4) * 8 + jb;
    const float4 v = *(const float4*)(src + (size_t)row * NL + k);
    float vv[4] = {v.x, v.y, v.z, v.w};
    bf16x4 h, l;
#pragma unroll
    for (int e = 0; e < 4; e++) {
        bf16 hh = (bf16)vv[e];
        h[e] = hh;
        l[e] = (bf16)(vv[e] - (float)hh);
    }
    *(bf16x4*)(hi + (size_t)t4 * 4) = h;
    *(bf16x4*)(lo + (size_t)t4 * 4) = l;
}

// inv[s][v] = last j with out_idx[s][j]==v, else -1 (numpy last-dup-wins)
__global__ void inv_kernel(const int* __restrict__ out_idx, int* __restrict__ inv) {
    int t = blockIdx.x * blockDim.x + threadIdx.x;
    if (t >= NS * V_) return;
    int s = t >> 6, v = t & 63;
    int jf = -1;
#pragma unroll
    for (int j = 0; j < NO; j++)
        if (out_idx[(s << 5) | j] == v) jf = j;
    inv[t] = jf;
}

__device__ __forceinline__ float fast_tanh(float z) {
    float e = __expf(2.0f * z);
    return 1.0f - 2.0f / (e + 1.0f);
}

// x fragment-order address for element (batch row n, k = t*16 + q*4):
__device__ __forceinline__ int xaddr(int t, int q, int n) {
    return ((t >> 1) * 512) + (((t & 1) * 2 + (q >> 1)) * 128) + n * 8 + (q & 1) * 4;
}

// ---------------------------------------------------------------------------
// Persistent per-block recurrence. RB=16 rows/block, 256 blocks, 16 waves.
// Wave w: GEMM1 col-tile w (16 cols, 24 MFMA, 4-deep weight-load ring);
//         GEMM2 task (t=w&1, ks=w>>1).
// One barrier/step; x double-buffered in frag order; Sp double-buffered.
// ---------------------------------------------------------------------------
__launch_bounds__(1024, 4)
__global__ void lalr_main(const float* __restrict__ latent0,
                          const float* __restrict__ b1,
                          const float* __restrict__ b2,
                          const int*   __restrict__ state_seq,
                          const int*   __restrict__ inv,
                          const bf16*  __restrict__ W1h, const bf16* __restrict__ W1l,
                          const bf16*  __restrict__ W2h, const bf16* __restrict__ W2l,
                          float* __restrict__ out) {
    __shared__ bf16  xh[2][4096];        // 16 KB  (frag order, double buffered)
    __shared__ bf16  xl[2][4096];        // 16 KB
    __shared__ float Sp[2][8][16][36];   // 72 KB  GEMM2 K-partials (pad 36)

    const int tid  = threadIdx.x;
    const int wave = tid >> 6;           // 0..15
    const int lane = tid & 63;
    const int n    = lane & 15;          // batch row
    const int q    = lane >> 4;          // quad
    const int r0   = blockIdx.x * RB;
    const int t2   = wave & 1;           // GEMM2 col-tile
    const int ks2  = wave >> 1;          // GEMM2 K-slice

    // ---- init: latent0 -> x[0] fragments (1 float4 per thread) ----
    {
        float4 v = *(const float4*)(latent0 + (size_t)(r0 + n) * NL + wave * 16 + q * 4);
        float vv[4] = {v.x, v.y, v.z, v.w};
        bf16x4 hv, lv;
#pragma unroll
        for (int e = 0; e < 4; e++) {
            bf16 hh = (bf16)vv[e];
            hv[e] = hh;
            lv[e] = (bf16)(vv[e] - (float)hh);
        }
        const int a = xaddr(wave, q, n);
        *(bf16x4*)(&xh[0][a]) = hv;
        *(bf16x4*)(&xl[0][a]) = lv;
    }

    int s0 = state_seq[0], s1 = -1, s2 = -1;

    // GEMM1 4-deep ring: preload ks=0..3 for s0
    bf16x8 pwh[4], pwl[4];
    const bf16* w1hb = W1h + ((size_t)(s0 * 16 + wave) * 8) * 512;
    const bf16* w1lb = W1l + ((size_t)(s0 * 16 + wave) * 8) * 512;
#pragma unroll
    for (int p = 0; p < 4; p++) {
        pwh[p] = *(const bf16x8*)(w1hb + p * 512 + lane * 8);
        pwl[p] = *(const bf16x8*)(w1lb + p * 512 + lane * 8);
    }
    bf16x8 w2h2, w2l2;   // GEMM2 frags for next iteration

    __syncthreads();

    for (int i = 0; i <= T_ + 1; i++) {
        const int ib = i & 1;
        const int cur = ib;               // x buffer read this iteration

        // ---- GEMM1 (state s0): col-tile `wave`, full K=256 ----
        f32x4 acc1;
        if (s0 >= 0) {
            acc1 = (f32x4){0.f, 0.f, 0.f, 0.f};
#pragma unroll
            for (int ks = 0; ks < 8; ks++) {
                bf16x8 xa = *(const bf16x8*)(&xh[cur][ks * 512 + lane * 8]);
                bf16x8 xb = *(const bf16x8*)(&xl[cur][ks * 512 + lane * 8]);
                const int sl = ks & 3;
                bf16x8 wh = pwh[sl], wl = pwl[sl];
                if (ks < 4) {
                    pwh[sl] = *(const bf16x8*)(w1hb + (ks + 4) * 512 + lane * 8);
                    pwl[sl] = *(const bf16x8*)(w1lb + (ks + 4) * 512 + lane * 8);
                }
                acc1 = MF(wh, xa, acc1);
                acc1 = MF(wl, xa, acc1);
                acc1 = MF(wh, xb, acc1);
            }
        }

        // ---- GEMM2 (state s1): task (t2, ks2) ----
        if (s1 >= 0) {
            bf16x8 xa = *(const bf16x8*)(&xh[cur][ks2 * 512 + lane * 8]);
            bf16x8 xb = *(const bf16x8*)(&xl[cur][ks2 * 512 + lane * 8]);
            f32x4 a2 = (f32x4){0.f, 0.f, 0.f, 0.f};
            a2 = MF(w2h2, xa, a2);
            a2 = MF(w2l2, xa, a2);
            a2 = MF(w2h2, xb, a2);
            if (ks2 == 0) {
                float4 bb = *(const float4*)(b2 + s1 * NO + t2 * 16 + q * 4);
                a2[0] += bb.x; a2[1] += bb.y; a2[2] += bb.z; a2[3] += bb.w;
            }
            *(f32x4*)(&Sp[ib][ks2][n][t2 * 16 + q * 4]) = a2;
        }

        // ---- cross-barrier prefetch for next iteration (issue early) ----
        const int ns0 = (i + 1 < T_) ? state_seq[i + 1] : -1;
        if (s0 >= 0) {   // next iteration's GEMM2 state = current s0
            const bf16* w2hb = W2h + ((size_t)((s0 * 2 + t2) * 8 + ks2)) * 512;
            const bf16* w2lb = W2l + ((size_t)((s0 * 2 + t2) * 8 + ks2)) * 512;
            w2h2 = *(const bf16x8*)(w2hb + lane * 8);
            w2l2 = *(const bf16x8*)(w2lb + lane * 8);
        }
        if (ns0 >= 0) {
            w1hb = W1h + ((size_t)(ns0 * 16 + wave) * 8) * 512;
            w1lb = W1l + ((size_t)(ns0 * 16 + wave) * 8) * 512;
#pragma unroll
            for (int p = 0; p < 4; p++) {
                pwh[p] = *(const bf16x8*)(w1hb + p * 512 + lane * 8);
                pwl[p] = *(const bf16x8*)(w1lb + p * 512 + lane * 8);
            }
        }

        // ---- softmax + shfl-scatter + store for step i-2 (first 4 waves) ----
        if (s2 >= 0 && tid < 256) {
            const int r  = tid >> 4;
            const int j0 = tid & 15;
            const int pb = (i - 1) & 1;
            float v0 = 0.f, v1 = 0.f;
#pragma unroll
            for (int w = 0; w < 8; w++) {
                v0 += Sp[pb][w][r][j0];
                v1 += Sp[pb][w][r][j0 + 16];
            }
            float m = fmaxf(v0, v1);
#pragma unroll
            for (int d = 1; d < 16; d <<= 1) m = fmaxf(m, __shfl_xor(m, d));
            float e0 = __expf(v0 - m), e1 = __expf(v1 - m);
            float su = e0 + e1;
#pragma unroll
            for (int d = 1; d < 16; d <<= 1) su += __shfl_xor(su, d);
            float is = 1.0f / su;
            float p0 = e0 * is, p1 = e1 * is;
            const int gb = lane & 48;     // 16-lane group base
            int4 iv4 = *(const int4*)(inv + s2 * V_ + j0 * 4);
            int ivv[4] = {iv4.x, iv4.y, iv4.z, iv4.w};
            float o[4];
#pragma unroll
            for (int e = 0; e < 4; e++) {
                float ga = __shfl(p0, gb + (ivv[e] & 15));
                float gc = __shfl(p1, gb + (ivv[e] & 15));
                o[e] = (ivv[e] < 0) ? 0.f : ((ivv[e] < 16) ? ga : gc);
            }
            *(float4*)(out + ((size_t)(r0 + r) * T_ + (i - 2)) * V_ + j0 * 4) = *(float4*)o;
        }

        // ---- tanh + hi/lo split -> x[cur^1] (1 col-tile per wave) ----
        if (s0 >= 0) {
            float4 bb = *(const float4*)(b1 + s0 * NL + wave * 16 + q * 4);
            float bv[4] = {bb.x, bb.y, bb.z, bb.w};
            bf16x4 hv, lv;
#pragma unroll
            for (int e = 0; e < 4; e++) {
                float h = fast_tanh(acc1[e] + bv[e]);
                bf16 hh = (bf16)h;
                hv[e] = hh;
                lv[e] = (bf16)(h - (float)hh);
            }
            const int a = xaddr(wave, q, n);
            *(bf16x4*)(&xh[cur ^ 1][a]) = hv;
            *(bf16x4*)(&xl[cur ^ 1][a]) = lv;
        }

        s2 = s1; s1 = s0; s0 = ns0;
        __syncthreads();
    }
}

extern "C" void kernel_launch(void* const* d_in, const int* in_sizes, int n_in,
                              void* d_out, int out_size, void* d_ws, size_t ws_size,
                              hipStream_t stream) {
    const float* latent0   = (const float*)d_in[0];
    const float* W1        = (const float*)d_in[1];
    const float* b1        = (const float*)d_in[2];
    const float* W2        = (const float*)d_in[3];
    const float* b2        = (const float*)d_in[4];
    const int*   state_seq = (const int*)d_in[5];
    const int*   out_idx   = (const int*)d_in[6];
    float* out = (float*)d_out;

    bf16* W1h = (bf16*)d_ws;
    bf16* W1l = W1h + (size_t)NS * NL * NL;
    bf16* W2h = W1l + (size_t)NS * NL * NL;
    bf16* W2l = W2h + (size_t)NS * NO * NL;
    int*  inv = (int*)(W2l + (size_t)NS * NO * NL);

    const int n4_w1 = NS * NL * NL / 4;   // 1,048,576
    const int n4_w2 = NS * NO * NL / 4;   // 131,072
    split_w_frag<4><<<n4_w1 / 256, 256, 0, stream>>>(W1, W1h, W1l, n4_w1);
    split_w_frag<1><<<n4_w2 / 256, 256, 0, stream>>>(W2, W2h, W2l, n4_w2);
    inv_kernel<<<(NS * V_ + 255) / 256, 256, 0, stream>>>(out_idx, inv);

    lalr_main<<<NBLK, 1024, 0, stream>>>(latent0, b1, b2, state_seq, inv,
                                         W1h, W1l, W2h, W2l, out);
}